// Round 1
// baseline (3175.234 us; speedup 1.0000x reference)
//
#include <hip/hip_runtime.h>

typedef _Float16 f16;
typedef _Float16 f16x8 __attribute__((ext_vector_type(8)));
typedef float f32x4 __attribute__((ext_vector_type(4)));

#define B_ 512
#define T_ 128
#define I_ 64
#define H_ 512
#define O_ 64
#define L_ 300
#define OUTSTR (L_*O_)   // 19200 floats per batch row of d_out

// ---------------------------------------------------------------------------
// Prologue kernels: convert x to fp16 [t][b][i], build fused/packed weights.
// Packed B layout (MFMA 16x16x32 f16 B-fragment order):
//   flat = ((ntile_global*KSTEPS + kstep)*64 + lane)*8 + elem
//   value = W[k][col] with k = kstep*32 + (lane>>4)*8 + elem, col = lane&15
// ---------------------------------------------------------------------------

__global__ void k_zero_h(f16* h) {
  int i = blockIdx.x*256 + threadIdx.x;
  if (i < B_*H_) h[i] = (f16)0.f;
}

__global__ void k_cvt_x(const float* __restrict__ x, f16* __restrict__ x16) {
  int p = blockIdx.x*256 + threadIdx.x;   // p = (t*512 + b)*64 + i
  if (p >= T_*B_*I_) return;
  int i = p & 63;
  int b = (p >> 6) & 511;
  int t = p >> 15;
  x16[p] = (f16)x[((size_t)b*T_ + t)*I_ + i];
}

// Wf[j3][k] = sum_o Wo[o][k] * Wih[j3][o]   (the folded y->gi path)
__global__ void k_fuse(const float* __restrict__ Wo, const float* __restrict__ Wih,
                       float* __restrict__ Wf) {
  int p = blockIdx.x*256 + threadIdx.x;
  if (p >= 1536*512) return;
  int k = p & 511, j3 = p >> 9;
  float s = 0.f;
  for (int o = 0; o < 64; ++o)
    s += Wo[(size_t)o*H_ + k] * Wih[(size_t)j3*I_ + o];
  Wf[p] = s;
}

// bf[j3] = sum_o bo[o] * Wih[j3][o]
__global__ void k_bf(const float* __restrict__ bo, const float* __restrict__ Wih,
                     float* __restrict__ bf) {
  int j3 = blockIdx.x*256 + threadIdx.x;
  if (j3 >= 1536) return;
  float s = 0.f;
  for (int o = 0; o < 64; ++o) s += bo[o]*Wih[(size_t)j3*I_ + o];
  bf[j3] = s;
}

// Encoder packed weights: 32 groups x 4 ntiles {r,z,hn,inn}, K=576 ([h|x]).
__global__ void k_pack_enc(const float* __restrict__ Whh, const float* __restrict__ Wih,
                           f16* __restrict__ We) {
  int p = blockIdx.x*256 + threadIdx.x;
  if (p >= 128*18*512) return;
  int i  = p & 7;
  int l  = (p >> 3) & 63;
  int ks = (p >> 9) % 18;
  int ntg = p / (18*512);
  int g = ntg >> 2, nti = ntg & 3;
  int c = l & 15;
  int j = g*16 + c;
  int k = ks*32 + ((l>>4)<<3) + i;
  float v = 0.f;
  if (nti == 0)      v = (k < 512) ? Whh[(size_t)j*H_ + k]          : Wih[(size_t)j*I_ + (k-512)];
  else if (nti == 1) v = (k < 512) ? Whh[(size_t)(512+j)*H_ + k]    : Wih[(size_t)(512+j)*I_ + (k-512)];
  else if (nti == 2) v = (k < 512) ? Whh[(size_t)(1024+j)*H_ + k]   : 0.f;
  else               v = (k >= 512)? Wih[(size_t)(1024+j)*I_ + (k-512)] : 0.f;
  We[p] = (f16)v;
}

// Decoder packed weights: 32 groups x 5 ntiles {r+f, z+f, hn, inn_f, y}, K=512.
__global__ void k_pack_dec(const float* __restrict__ Whh, const float* __restrict__ Wo,
                           const float* __restrict__ Wf, f16* __restrict__ Wd) {
  int p = blockIdx.x*256 + threadIdx.x;
  if (p >= 160*16*512) return;
  int i  = p & 7;
  int l  = (p >> 3) & 63;
  int ks = (p >> 9) & 15;
  int ntg = p >> 13;
  int g = ntg/5, nti = ntg%5;
  int c = l & 15;
  int j = g*16 + c;
  int k = ks*32 + ((l>>4)<<3) + i;
  float v;
  if (nti == 0)      v = Whh[(size_t)j*H_+k]        + Wf[(size_t)j*512 + k];
  else if (nti == 1) v = Whh[(size_t)(512+j)*H_+k]  + Wf[(size_t)(512+j)*512 + k];
  else if (nti == 2) v = Whh[(size_t)(1024+j)*H_+k];
  else if (nti == 3) v = Wf[(size_t)(1024+j)*512 + k];
  else               v = (c < 2) ? Wo[(size_t)(2*g+c)*H_ + k] : 0.f;
  Wd[p] = (f16)v;
}

__global__ void k_bias_enc(const float* __restrict__ bih, const float* __restrict__ bhh,
                           float* __restrict__ be) {
  int p = blockIdx.x*256 + threadIdx.x;
  if (p >= 2048) return;
  int c = p & 15, ntg = p >> 4, g = ntg >> 2, nti = ntg & 3, j = g*16 + c;
  float v;
  if (nti == 0)      v = bih[j] + bhh[j];
  else if (nti == 1) v = bih[512+j] + bhh[512+j];
  else if (nti == 2) v = bhh[1024+j];
  else               v = bih[1024+j];
  be[p] = v;
}

__global__ void k_bias_dec(const float* __restrict__ bih, const float* __restrict__ bhh,
                           const float* __restrict__ bo, const float* __restrict__ bf,
                           float* __restrict__ bd) {
  int p = blockIdx.x*256 + threadIdx.x;
  if (p >= 2560) return;
  int c = p & 15, ntg = p >> 4, g = ntg/5, nti = ntg%5, j = g*16 + c;
  float v;
  if (nti == 0)      v = bih[j] + bhh[j] + bf[j];
  else if (nti == 1) v = bih[512+j] + bhh[512+j] + bf[512+j];
  else if (nti == 2) v = bhh[1024+j];
  else if (nti == 3) v = bih[1024+j] + bf[1024+j];
  else               v = (c < 2) ? bo[2*g+c] : 0.f;
  bd[p] = v;
}

// ---------------------------------------------------------------------------
// Per-step kernels. grid = (32 col-groups, 8 row-groups), 256 threads (4 waves).
// Wave w handles rows [bm*64 + 16w, +16). Block's 64/80 N-cols are the 16-col
// gate groups {r,z,hn,inn(,y)} for h-cols [16g,16g+16) -> gates fuse locally.
// ---------------------------------------------------------------------------

__device__ __forceinline__ float sigmoidf_(float x){ return 1.f/(1.f + __expf(-x)); }

__global__ __launch_bounds__(256) void k_enc_step(
    const f16* __restrict__ h_in, const f16* __restrict__ xt,
    const f16* __restrict__ We, const float* __restrict__ be,
    f16* __restrict__ h_out) {
  __shared__ f16 lds[4*9*512];            // 36864 B: 4 ntiles x 9 ksteps x 1KB
  const int tid = threadIdx.x, w = tid >> 6, lane = tid & 63;
  const int g = blockIdx.x, bm = blockIdx.y;
  const int c = lane & 15, rq = lane >> 4;
  const int row0 = bm*64 + w*16 + c;      // A-fragment row
  f32x4 acc[4] = {};

  for (int chunk = 0; chunk < 2; ++chunk) {
    if (chunk) __syncthreads();
    const int ks0 = chunk*9;
    #pragma unroll
    for (int it = 0; it < 9; ++it) {      // stage 36864B, linear 16B copies
      int idx = it*256 + tid;             // 0..2303
      int nt = idx / 576, r = idx % 576;
      const char* src = (const char*)We + (size_t)(g*4+nt)*18432 + (size_t)ks0*1024 + (size_t)r*16;
      *(f16x8*)((char*)lds + (size_t)idx*16) = *(const f16x8*)src;
    }
    __syncthreads();
    for (int ks = 0; ks < 9; ++ks) {
      int kk = (ks0 + ks)*32 + (rq << 3);
      f16x8 a;
      if (kk < 512) a = *(const f16x8*)(h_in + (size_t)row0*H_ + kk);
      else          a = *(const f16x8*)(xt   + (size_t)row0*I_ + (kk - 512));
      #pragma unroll
      for (int nt = 0; nt < 4; ++nt) {
        f16x8 b = *(const f16x8*)(lds + (size_t)(nt*9 + ks)*512 + lane*8);
        acc[nt] = __builtin_amdgcn_mfma_f32_16x16x32_f16(a, b, acc[nt], 0, 0, 0);
      }
    }
  }

  int j = g*16 + c;
  float br = be[(g*4+0)*16 + c], bz = be[(g*4+1)*16 + c];
  float bh = be[(g*4+2)*16 + c], bi = be[(g*4+3)*16 + c];
  #pragma unroll
  for (int i = 0; i < 4; ++i) {
    int row = bm*64 + w*16 + rq*4 + i;    // C/D: col=lane&15, row=(lane>>4)*4+i
    float r = sigmoidf_(acc[0][i] + br);
    float z = sigmoidf_(acc[1][i] + bz);
    float n = tanhf((acc[3][i] + bi) + r*(acc[2][i] + bh));
    float hp = (float)h_in[(size_t)row*H_ + j];
    h_out[(size_t)row*H_ + j] = (f16)((1.f - z)*n + z*hp);
  }
}

__global__ __launch_bounds__(256) void k_dec_step(
    const f16* __restrict__ h_in, const f16* __restrict__ Wd,
    const float* __restrict__ bd, f16* __restrict__ h_out,
    float* __restrict__ yout) {          // yout = d_out + t*64 (y of h_in)
  __shared__ f16 lds[5*8*512];            // 40960 B: 5 ntiles x 8 ksteps x 1KB
  const int tid = threadIdx.x, w = tid >> 6, lane = tid & 63;
  const int g = blockIdx.x, bm = blockIdx.y;
  const int c = lane & 15, rq = lane >> 4;
  const int row0 = bm*64 + w*16 + c;
  f32x4 acc[5] = {};

  for (int chunk = 0; chunk < 2; ++chunk) {
    if (chunk) __syncthreads();
    const int ks0 = chunk*8;
    #pragma unroll
    for (int it = 0; it < 10; ++it) {     // stage 40960B
      int idx = it*256 + tid;             // 0..2559
      int nt = idx >> 9, r = idx & 511;
      const char* src = (const char*)Wd + (size_t)(g*5+nt)*16384 + (size_t)ks0*1024 + (size_t)r*16;
      *(f16x8*)((char*)lds + (size_t)idx*16) = *(const f16x8*)src;
    }
    __syncthreads();
    for (int ks = 0; ks < 8; ++ks) {
      int kk = (ks0 + ks)*32 + (rq << 3);
      f16x8 a = *(const f16x8*)(h_in + (size_t)row0*H_ + kk);
      #pragma unroll
      for (int nt = 0; nt < 5; ++nt) {
        f16x8 b = *(const f16x8*)(lds + (size_t)(nt*8 + ks)*512 + lane*8);
        acc[nt] = __builtin_amdgcn_mfma_f32_16x16x32_f16(a, b, acc[nt], 0, 0, 0);
      }
    }
  }

  int j = g*16 + c;
  float br = bd[(g*5+0)*16 + c], bz = bd[(g*5+1)*16 + c];
  float bh = bd[(g*5+2)*16 + c], bi = bd[(g*5+3)*16 + c];
  float by = bd[(g*5+4)*16 + c];
  #pragma unroll
  for (int i = 0; i < 4; ++i) {
    int row = bm*64 + w*16 + rq*4 + i;
    float r = sigmoidf_(acc[0][i] + br);
    float z = sigmoidf_(acc[1][i] + bz);
    float n = tanhf((acc[3][i] + bi) + r*(acc[2][i] + bh));
    float hp = (float)h_in[(size_t)row*H_ + j];
    h_out[(size_t)row*H_ + j] = (f16)((1.f - z)*n + z*hp);
    if (c < 2) {                          // y_t = h_in @ Wo.T + bo (2 cols/group)
      yout[(size_t)row*OUTSTR + (2*g + c)] = acc[4][i] + by;
    }
  }
}

__global__ void k_final_y(const f16* __restrict__ h, const float* __restrict__ Wo,
                          const float* __restrict__ bo, float* __restrict__ out) {
  int idx = blockIdx.x*256 + threadIdx.x; // 32768 = 512*64
  int b = idx >> 6, o = idx & 63;
  float s = bo[o];
  for (int k = 0; k < H_; ++k)
    s += (float)h[(size_t)b*H_ + k] * Wo[(size_t)o*H_ + k];
  out[(size_t)b*OUTSTR + (size_t)(L_-1)*O_ + o] = s;
}

// ---------------------------------------------------------------------------

extern "C" void kernel_launch(void* const* d_in, const int* in_sizes, int n_in,
                              void* d_out, int out_size, void* d_ws, size_t ws_size,
                              hipStream_t stream) {
  (void)in_sizes; (void)n_in; (void)out_size; (void)ws_size;
  const float* x   = (const float*)d_in[0];
  const float* Wih = (const float*)d_in[1];
  const float* Whh = (const float*)d_in[2];
  const float* bih = (const float*)d_in[3];
  const float* bhh = (const float*)d_in[4];
  const float* Wo  = (const float*)d_in[5];
  const float* bo  = (const float*)d_in[6];
  float* out = (float*)d_out;

  char* ws = (char*)d_ws;
  size_t off = 0;
  auto alloc = [&](size_t bytes) {
    char* p = ws + off;
    off += (bytes + 255) & ~(size_t)255;
    return p;
  };
  f16*   x16 = (f16*)  alloc((size_t)T_*B_*I_*2);      // 8.39 MB, [t][b][i]
  f16*   hA  = (f16*)  alloc((size_t)B_*H_*2);
  f16*   hB  = (f16*)  alloc((size_t)B_*H_*2);
  f16*   We  = (f16*)  alloc((size_t)128*18*512*2);    // enc packed (K=576,N=2048)
  f16*   Wd  = (f16*)  alloc((size_t)160*16*512*2);    // dec packed (K=512,N=2560 incl y-pad)
  float* Wf  = (float*)alloc((size_t)1536*512*4);      // fused Wo.T@Wih.T
  float* be  = (float*)alloc(2048*4);
  float* bd  = (float*)alloc(2560*4);
  float* bf  = (float*)alloc(1536*4);

  hipLaunchKernelGGL(k_zero_h,   dim3((B_*H_+255)/256),     dim3(256), 0, stream, hA);
  hipLaunchKernelGGL(k_cvt_x,    dim3((T_*B_*I_+255)/256),  dim3(256), 0, stream, x, x16);
  hipLaunchKernelGGL(k_fuse,     dim3(1536*512/256),        dim3(256), 0, stream, Wo, Wih, Wf);
  hipLaunchKernelGGL(k_bf,       dim3(6),                   dim3(256), 0, stream, bo, Wih, bf);
  hipLaunchKernelGGL(k_pack_enc, dim3(128*18*512/256),      dim3(256), 0, stream, Whh, Wih, We);
  hipLaunchKernelGGL(k_pack_dec, dim3(160*16*512/256),      dim3(256), 0, stream, Whh, Wo, Wf, Wd);
  hipLaunchKernelGGL(k_bias_enc, dim3(8),                   dim3(256), 0, stream, bih, bhh, be);
  hipLaunchKernelGGL(k_bias_dec, dim3(10),                  dim3(256), 0, stream, bih, bhh, bo, bf, bd);

  f16* hin = hA;
  f16* hout = hB;
  for (int t = 0; t < T_; ++t) {
    hipLaunchKernelGGL(k_enc_step, dim3(32, 8), dim3(256), 0, stream,
                       hin, x16 + (size_t)t*B_*I_, We, be, hout);
    f16* tmp = hin; hin = hout; hout = tmp;
  }
  for (int k = 1; k < L_; ++k) {
    hipLaunchKernelGGL(k_dec_step, dim3(32, 8), dim3(256), 0, stream,
                       hin, Wd, bd, hout, out + (size_t)(k-1)*O_);
    f16* tmp = hin; hin = hout; hout = tmp;
  }
  hipLaunchKernelGGL(k_final_y, dim3(B_*O_/256), dim3(256), 0, stream, hin, Wo, bo, out);
}